// Round 1
// baseline (9536.737 us; speedup 1.0000x reference)
//
#include <hip/hip_runtime.h>
#include <math.h>

// ============================================================================
// AuroraBlock: 4096 positions (B=4,T=1024), each with N=16 slots of DR=256.
// Round 0: correct f32 baseline.
//   ws layout (floats):
//     [0 .. 65535]           slot mask  (B*T*N)
//     [65536 .. 69631]       sproj      (B*T)
//     [69632 .. 81919]       probs      (B*T*3)
//     [81920 .. 81923]       accum[4] = sum_p0,sum_p1,sum_p2,sum_k
//     [131072 .. 131072+16777215]  r_cur (B,T,N,DR)
//   d_out: [0..16777215] r_out, [16777216] routing_loss, [16777217] mean_k
// ============================================================================

#define NPOS 4096
#define R_ELEMS 16777216ull

__device__ __forceinline__ float gelu_tanh(float x) {
  float x3 = x * x * x;
  float t = tanhf(0.79788456080286536f * (x + 0.044715f * x3));
  return 0.5f * x * (1.f + t);
}

__global__ void init_accum_kernel(float* accum) {
  if (threadIdx.x < 4) accum[threadIdx.x] = 0.f;
}

// sproj[p] = dot(s[p,:], Ws)   (block of 256 per position)
__global__ void sproj_kernel(const float* __restrict__ s, const float* __restrict__ Ws,
                             float* __restrict__ sproj) {
  int p = blockIdx.x, tid = threadIdx.x;
  const float* row = s + (size_t)p * 1024;
  float sum = 0.f;
#pragma unroll
  for (int k0 = 0; k0 < 1024; k0 += 256) sum += row[k0 + tid] * Ws[k0 + tid];
#pragma unroll
  for (int m = 1; m < 64; m <<= 1) sum += __shfl_xor(sum, m, 64);
  __shared__ float red[4];
  if ((tid & 63) == 0) red[tid >> 6] = sum;
  __syncthreads();
  if (tid == 0) sproj[p] = red[0] + red[1] + red[2] + red[3];
}

// probs[p][0..2] = softmax(relu(s@Wd1+bd1)@Wd2+bd2); atomics into accum
__global__ void difficulty_kernel(const float* __restrict__ s, const float* __restrict__ Wd1,
                                  const float* __restrict__ bd1, const float* __restrict__ Wd2,
                                  const float* __restrict__ bd2, float* __restrict__ probsv,
                                  float* __restrict__ accum) {
  int p = blockIdx.x, tid = threadIdx.x;  // 128 threads
  __shared__ float s_sh[1024];
  __shared__ float hid_sh[128];
  __shared__ float log_sh[3];
  const float* row = s + (size_t)p * 1024;
  for (int k = tid; k < 1024; k += 128) s_sh[k] = row[k];
  __syncthreads();
  float acc = bd1[tid];
  for (int k = 0; k < 1024; k += 4) {
    float4 sv = *(const float4*)&s_sh[k];
    acc += sv.x * Wd1[(k + 0) * 128 + tid] + sv.y * Wd1[(k + 1) * 128 + tid] +
           sv.z * Wd1[(k + 2) * 128 + tid] + sv.w * Wd1[(k + 3) * 128 + tid];
  }
  hid_sh[tid] = fmaxf(acc, 0.f);
  __syncthreads();
  if (tid < 3) {
    float l = bd2[tid];
    for (int k = 0; k < 128; ++k) l += hid_sh[k] * Wd2[k * 3 + tid];
    log_sh[tid] = l;
  }
  __syncthreads();
  if (tid == 0) {
    float l0 = log_sh[0], l1 = log_sh[1], l2 = log_sh[2];
    float mx = fmaxf(l0, fmaxf(l1, l2));
    float e0 = expf(l0 - mx), e1 = expf(l1 - mx), e2 = expf(l2 - mx);
    float inv = 1.f / (e0 + e1 + e2);
    float p0 = e0 * inv, p1 = e1 * inv, p2 = e2 * inv;
    probsv[p * 3 + 0] = p0; probsv[p * 3 + 1] = p1; probsv[p * 3 + 2] = p2;
    atomicAdd(accum + 0, p0);
    atomicAdd(accum + 1, p1);
    atomicAdd(accum + 2, p2);
    atomicAdd(accum + 3, p0 * 1.f + p1 * 2.f + p2 * 4.f);
  }
}

// mask[row] = sigmoid(relu(r_row@Wa1+ba1)@Wa2 + ba2 + sproj[row/16])
__global__ void slot_mask_kernel(const float* __restrict__ r, const float* __restrict__ Wa1,
                                 const float* __restrict__ ba1, const float* __restrict__ Wa2,
                                 const float* __restrict__ ba2, const float* __restrict__ sproj,
                                 float* __restrict__ mask) {
  int row = blockIdx.x, tid = threadIdx.x;  // 128 threads
  __shared__ float r_sh[256];
  __shared__ float red[2];
  const float* rr = r + (size_t)row * 256;
  for (int k = tid; k < 256; k += 128) r_sh[k] = rr[k];
  __syncthreads();
  float acc = ba1[tid];
  for (int k = 0; k < 256; k += 4) {
    float4 rv = *(const float4*)&r_sh[k];
    acc += rv.x * Wa1[(k + 0) * 128 + tid] + rv.y * Wa1[(k + 1) * 128 + tid] +
           rv.z * Wa1[(k + 2) * 128 + tid] + rv.w * Wa1[(k + 3) * 128 + tid];
  }
  float val = fmaxf(acc, 0.f) * Wa2[tid];
#pragma unroll
  for (int m = 1; m < 64; m <<= 1) val += __shfl_xor(val, m, 64);
  if ((tid & 63) == 0) red[tid >> 6] = val;
  __syncthreads();
  if (tid == 0) {
    float tot = red[0] + red[1] + ba2[0] + sproj[row >> 4];
    mask[row] = 1.f / (1.f + expf(-tot));
  }
}

// A(16x256 in LDS) @ W(256 x ldw, column window colofs..) -> acc0/acc1 (8 rows x 2 cols)
// thread: rh = tid>>7 selects rows rh*8..rh*8+7 ; col = tid&127 ; cols col and col+128
__device__ __forceinline__ void matmul16_8x2(const float (*A)[256], const float* __restrict__ W,
                                             int ldw, int colofs, float* acc0, float* acc1,
                                             int rh, int col) {
  for (int kk = 0; kk < 256; kk += 4) {
    float w0[4], w1[4];
#pragma unroll
    for (int i = 0; i < 4; ++i) {
      w0[i] = W[(size_t)(kk + i) * ldw + colofs + col];
      w1[i] = W[(size_t)(kk + i) * ldw + colofs + col + 128];
    }
#pragma unroll
    for (int n = 0; n < 8; ++n) {
      float4 a = *(const float4*)&A[rh * 8 + n][kk];
      acc0[n] += a.x * w0[0] + a.y * w0[1] + a.z * w0[2] + a.w * w0[3];
      acc1[n] += a.x * w1[0] + a.y * w1[1] + a.z * w1[2] + a.w * w1[3];
    }
  }
}

__device__ __forceinline__ void layernorm16(const float (*src)[256], float (*dst)[256],
                                            const float* __restrict__ sc,
                                            const float* __restrict__ bi, int tid) {
  int n = tid >> 4, j0 = (tid & 15) * 16;
  float vals[16];
  float sum = 0.f, sq = 0.f;
#pragma unroll
  for (int k = 0; k < 16; k += 4) {
    float4 v4 = *(const float4*)&src[n][j0 + k];
    vals[k] = v4.x; vals[k + 1] = v4.y; vals[k + 2] = v4.z; vals[k + 3] = v4.w;
    sum += v4.x + v4.y + v4.z + v4.w;
    sq += v4.x * v4.x + v4.y * v4.y + v4.z * v4.z + v4.w * v4.w;
  }
#pragma unroll
  for (int m = 1; m < 16; m <<= 1) {
    sum += __shfl_xor(sum, m, 64);
    sq += __shfl_xor(sq, m, 64);
  }
  float mu = sum * (1.f / 256.f);
  float inv = rsqrtf(sq * (1.f / 256.f) - mu * mu + 1e-5f);
#pragma unroll
  for (int k = 0; k < 16; ++k) {
    int j = j0 + k;
    dst[n][j] = (vals[k] - mu) * inv * sc[j] + bi[j];
  }
}

__global__ __launch_bounds__(256, 2) void reason_step(
    const float* __restrict__ r_src, float* __restrict__ r_dst,
    const float* __restrict__ maskg, const float* __restrict__ probsv,
    float* __restrict__ outp, int cand_idx,
    const float* __restrict__ Wq, const float* __restrict__ Wk,
    const float* __restrict__ Wv, const float* __restrict__ Wo,
    const float* __restrict__ ln1s, const float* __restrict__ ln1b,
    const float* __restrict__ ln2s, const float* __restrict__ ln2b,
    const float* __restrict__ Wf1, const float* __restrict__ bf1,
    const float* __restrict__ Wf2, const float* __restrict__ bf2) {
  __shared__ float r_s[16][256];
  __shared__ float h_s[16][256];
  __shared__ float a_s[16][256];  // q, later o
  __shared__ float b_s[16][256];  // k, later v, later ffn-hidden chunk
  __shared__ float att_s[4][16][16];
  __shared__ float mask_s[16];
  const int p = blockIdx.x, tid = threadIdx.x;
  const int rh = tid >> 7, col = tid & 127;
  const size_t base = (size_t)p * 4096;

  for (int n = 0; n < 16; ++n) r_s[n][tid] = r_src[base + n * 256 + tid];
  if (tid < 16) mask_s[tid] = maskg[p * 16 + tid];
  __syncthreads();

  // ---- h = LN1(r) ----
  layernorm16(r_s, h_s, ln1s, ln1b, tid);
  __syncthreads();

  // ---- q -> a_s, k -> b_s ----
  {
    float q0[8] = {0}, q1[8] = {0}, k0[8] = {0}, k1[8] = {0};
    matmul16_8x2(h_s, Wq, 256, 0, q0, q1, rh, col);
    matmul16_8x2(h_s, Wk, 256, 0, k0, k1, rh, col);
#pragma unroll
    for (int n = 0; n < 8; ++n) {
      a_s[rh * 8 + n][col] = q0[n]; a_s[rh * 8 + n][col + 128] = q1[n];
      b_s[rh * 8 + n][col] = k0[n]; b_s[rh * 8 + n][col + 128] = k1[n];
    }
  }
  __syncthreads();

  // ---- scores = q.k^T / 8 per head ----
  {
    int hh = tid >> 6, idx = tid & 63, n = idx >> 2, m0 = idx & 3;
    float sc[4] = {0.f, 0.f, 0.f, 0.f};
    for (int d = 0; d < 64; d += 4) {
      float4 qv = *(const float4*)&a_s[n][hh * 64 + d];
#pragma unroll
      for (int mi = 0; mi < 4; ++mi) {
        float4 kv = *(const float4*)&b_s[m0 + mi * 4][hh * 64 + d];
        sc[mi] += qv.x * kv.x + qv.y * kv.y + qv.z * kv.z + qv.w * kv.w;
      }
    }
#pragma unroll
    for (int mi = 0; mi < 4; ++mi) att_s[hh][n][m0 + mi * 4] = sc[mi] * 0.125f;
  }
  __syncthreads();

  // ---- softmax rows (tid<64) overlapped with v = h@Wv -> regs ----
  if (tid < 64) {
    int hh = tid >> 4, n = tid & 15;
    float mx = -1e30f;
#pragma unroll
    for (int m = 0; m < 16; ++m) mx = fmaxf(mx, att_s[hh][n][m]);
    float ssum = 0.f; float e[16];
#pragma unroll
    for (int m = 0; m < 16; ++m) { e[m] = expf(att_s[hh][n][m] - mx); ssum += e[m]; }
    float inv = 1.f / ssum;
#pragma unroll
    for (int m = 0; m < 16; ++m) att_s[hh][n][m] = e[m] * inv;
  }
  {
    float v0[8] = {0}, v1[8] = {0};
    matmul16_8x2(h_s, Wv, 256, 0, v0, v1, rh, col);
    __syncthreads();  // k fully consumed (scores barrier) + softmax done
#pragma unroll
    for (int n = 0; n < 8; ++n) {
      b_s[rh * 8 + n][col] = v0[n]; b_s[rh * 8 + n][col + 128] = v1[n];
    }
  }
  __syncthreads();

  // ---- o = attn @ v -> a_s (overwrites q) ----
  {
    int hh0 = col >> 6, hh1 = (col + 128) >> 6;
    float s0[8] = {0}, s1[8] = {0};
    for (int m = 0; m < 16; ++m) {
      float v0 = b_s[m][col], v1 = b_s[m][col + 128];
#pragma unroll
      for (int n = 0; n < 8; ++n) {
        s0[n] += att_s[hh0][rh * 8 + n][m] * v0;
        s1[n] += att_s[hh1][rh * 8 + n][m] * v1;
      }
    }
#pragma unroll
    for (int n = 0; n < 8; ++n) {
      a_s[rh * 8 + n][col] = s0[n]; a_s[rh * 8 + n][col + 128] = s1[n];
    }
  }
  __syncthreads();

  // ---- r += mask * (o @ Wo) ----
  {
    float c0[8] = {0}, c1[8] = {0};
    matmul16_8x2(a_s, Wo, 256, 0, c0, c1, rh, col);
#pragma unroll
    for (int n = 0; n < 8; ++n) {
      r_s[rh * 8 + n][col] += mask_s[rh * 8 + n] * c0[n];
      r_s[rh * 8 + n][col + 128] += mask_s[rh * 8 + n] * c1[n];
    }
  }
  __syncthreads();

  // ---- h2 = LN2(r) ----
  layernorm16(r_s, h_s, ln2s, ln2b, tid);
  __syncthreads();

  // ---- FFN: r += mask * (gelu(h2@Wf1+bf1)@Wf2 + bf2), chunked over hidden ----
  {
    float fa0[8] = {0}, fa1[8] = {0};
    for (int ch = 0; ch < 4; ++ch) {
      float hc0[8] = {0}, hc1[8] = {0};
      matmul16_8x2(h_s, Wf1, 1024, ch * 256, hc0, hc1, rh, col);
      __syncthreads();  // previous chunk of b_s fully consumed
      float bb0 = bf1[ch * 256 + col], bb1 = bf1[ch * 256 + col + 128];
#pragma unroll
      for (int n = 0; n < 8; ++n) {
        b_s[rh * 8 + n][col] = gelu_tanh(hc0[n] + bb0);
        b_s[rh * 8 + n][col + 128] = gelu_tanh(hc1[n] + bb1);
      }
      __syncthreads();
      const float* W2 = Wf2 + (size_t)ch * 256 * 256;
      for (int kk = 0; kk < 256; kk += 4) {
        float w0[4], w1[4];
#pragma unroll
        for (int i = 0; i < 4; ++i) {
          w0[i] = W2[(size_t)(kk + i) * 256 + col];
          w1[i] = W2[(size_t)(kk + i) * 256 + col + 128];
        }
#pragma unroll
        for (int n = 0; n < 8; ++n) {
          float4 a = *(const float4*)&b_s[rh * 8 + n][kk];
          fa0[n] += a.x * w0[0] + a.y * w0[1] + a.z * w0[2] + a.w * w0[3];
          fa1[n] += a.x * w1[0] + a.y * w1[1] + a.z * w1[2] + a.w * w1[3];
        }
      }
    }
    float b20 = bf2[col], b21 = bf2[col + 128];
#pragma unroll
    for (int n = 0; n < 8; ++n) {
      r_s[rh * 8 + n][col] += mask_s[rh * 8 + n] * (fa0[n] + b20);
      r_s[rh * 8 + n][col + 128] += mask_s[rh * 8 + n] * (fa1[n] + b21);
    }
  }
  __syncthreads();

  // ---- store r_next; accumulate candidate into out ----
  {
    float w = (cand_idx >= 0) ? probsv[p * 3 + cand_idx] : 0.f;
    for (int n = 0; n < 16; ++n) {
      float v = r_s[n][tid];
      r_dst[base + n * 256 + tid] = v;
      if (cand_idx == 0)
        outp[base + n * 256 + tid] = w * v;
      else if (cand_idx > 0)
        outp[base + n * 256 + tid] += w * v;
    }
  }
}

__global__ void finalize_kernel(const float* __restrict__ accum, float* __restrict__ dst) {
  const float inv = 1.f / 4096.f;
  float m0 = accum[0] * inv, m1 = accum[1] * inv, m2 = accum[2] * inv;
  const float u = 1.f / 3.f;
  float d0 = m0 - u, d1 = m1 - u, d2 = m2 - u;
  dst[0] = (d0 * d0 + d1 * d1 + d2 * d2) * (1.f / 3.f);
  dst[1] = accum[3] * inv;
}

extern "C" void kernel_launch(void* const* d_in, const int* in_sizes, int n_in,
                              void* d_out, int out_size, void* d_ws, size_t ws_size,
                              hipStream_t stream) {
  const float* s    = (const float*)d_in[0];
  const float* r    = (const float*)d_in[1];
  const float* Wd1  = (const float*)d_in[2];
  const float* bd1  = (const float*)d_in[3];
  const float* Wd2  = (const float*)d_in[4];
  const float* bd2  = (const float*)d_in[5];
  const float* Wa1  = (const float*)d_in[6];
  const float* ba1  = (const float*)d_in[7];
  const float* Wa2  = (const float*)d_in[8];
  const float* ba2  = (const float*)d_in[9];
  const float* Wsp  = (const float*)d_in[10];
  const float* ln1s = (const float*)d_in[11];
  const float* ln1b = (const float*)d_in[12];
  const float* Wq   = (const float*)d_in[13];
  const float* Wk   = (const float*)d_in[14];
  const float* Wv   = (const float*)d_in[15];
  const float* Wo   = (const float*)d_in[16];
  const float* ln2s = (const float*)d_in[17];
  const float* ln2b = (const float*)d_in[18];
  const float* Wf1  = (const float*)d_in[19];
  const float* bf1  = (const float*)d_in[20];
  const float* Wf2  = (const float*)d_in[21];
  const float* bf2  = (const float*)d_in[22];

  float* out = (float*)d_out;
  float* wsf = (float*)d_ws;
  float* mask   = wsf;                        // 65536
  float* sproj  = wsf + 65536;                // 4096
  float* probsv = wsf + 65536 + 4096;         // 12288
  float* accum  = wsf + 65536 + 4096 + 12288; // 4
  float* r_cur  = wsf + 131072;               // 16777216

  init_accum_kernel<<<1, 64, 0, stream>>>(accum);
  sproj_kernel<<<NPOS, 256, 0, stream>>>(s, Wsp, sproj);
  difficulty_kernel<<<NPOS, 128, 0, stream>>>(s, Wd1, bd1, Wd2, bd2, probsv, accum);
  slot_mask_kernel<<<NPOS * 16, 128, 0, stream>>>(r, Wa1, ba1, Wa2, ba2, sproj, mask);

  // step 1 (candidate 0): input r -> r_cur
  reason_step<<<NPOS, 256, 0, stream>>>(r, r_cur, mask, probsv, out, 0,
                                        Wq, Wk, Wv, Wo, ln1s, ln1b, ln2s, ln2b,
                                        Wf1, bf1, Wf2, bf2);
  // step 2 (candidate 1)
  reason_step<<<NPOS, 256, 0, stream>>>(r_cur, r_cur, mask, probsv, out, 1,
                                        Wq, Wk, Wv, Wo, ln1s, ln1b, ln2s, ln2b,
                                        Wf1, bf1, Wf2, bf2);
  // step 3 (no candidate)
  reason_step<<<NPOS, 256, 0, stream>>>(r_cur, r_cur, mask, probsv, out, -1,
                                        Wq, Wk, Wv, Wo, ln1s, ln1b, ln2s, ln2b,
                                        Wf1, bf1, Wf2, bf2);
  // step 4 (candidate 2)
  reason_step<<<NPOS, 256, 0, stream>>>(r_cur, r_cur, mask, probsv, out, 2,
                                        Wq, Wk, Wv, Wo, ln1s, ln1b, ln2s, ln2b,
                                        Wf1, bf1, Wf2, bf2);

  finalize_kernel<<<1, 1, 0, stream>>>(accum, out + R_ELEMS);
}

// Round 2
// 2095.207 us; speedup vs baseline: 4.5517x; 4.5517x over previous
//
#include <hip/hip_runtime.h>
#include <math.h>

// ============================================================================
// AuroraBlock round 2: MFMA bf16 per-position fused reasoning steps.
//   - one wave per position; sigma(g,jj)=4g+(jj&3)+16(jj>>2) k-packing so
//     C-layout outputs chain directly into next MFMA operands (no shuffles).
//   - weights pre-packed to bf16 fragment order in ws (pack_weight kernel).
//   - r resident in XOR-swizzled LDS (f32); residuals/LN read-modify there.
// ws layout (floats):
//   [0..65535] mask | [65536..69631] sproj | [69632..81919] probs
//   [81920..81923] accum | [131072 .. +16777215] r_cur
//   shorts at float offset 16908288: packed Wq,Wk,Wv,Wo,Wf1,Wf2,Wa1,Wd1
// d_out: [0..16777215] r_out, [16777216] routing_loss, [16777217] mean_k
// ============================================================================

#define NPOS 4096
#define R_ELEMS 16777216ull

typedef __attribute__((ext_vector_type(8))) short short8;
typedef __attribute__((ext_vector_type(4))) float f32x4;

#define MF(a, b, c) __builtin_amdgcn_mfma_f32_16x16x32_bf16(a, b, c, 0, 0, 0)

__device__ __forceinline__ short bf16rne(float f) {
  union { float f; unsigned u; } v; v.f = f;
  unsigned r = v.u + 0x7FFFu + ((v.u >> 16) & 1u);
  return (short)(r >> 16);
}

__device__ __forceinline__ float fast_gelu(float x) {
  float x3 = x * x * x;
  float z = 0.7978845608028654f * (x + 0.044715f * x3);
  float e = __expf(2.f * z);          // tanh(z) = 1 - 2/(e^{2z}+1)
  float t = 1.f - 2.f / (e + 1.f);
  return 0.5f * x * (1.f + t);
}

// universal fragment packing: P[t][kc][lane][jj] = W[32kc+4g+(jj&3)+16(jj>>2)][16t+n]
__global__ void pack_weight(const float* __restrict__ W, short* __restrict__ P,
                            int K, int N) {
  int id = blockIdx.x * 256 + threadIdx.x;
  int KC = K >> 5, T = N >> 4;
  if (id >= T * KC * 64) return;
  int l = id & 63, kc = (id >> 6) % KC, t = id / (64 * KC);
  int g = l >> 4, n = l & 15;
  short8 o;
#pragma unroll
  for (int jj = 0; jj < 8; jj++) {
    int k = 32 * kc + 4 * g + (jj & 3) + 16 * (jj >> 2);
    o[jj] = bf16rne(W[(size_t)k * N + 16 * t + n]);
  }
  *(short8*)(P + (size_t)id * 8) = o;
}

__device__ __forceinline__ short8 ldfrag(const short* __restrict__ P, int t, int kc,
                                         int KC, int lane) {
  return *(const short8*)(P + ((size_t)((t * KC + kc) * 64 + lane) << 3));
}

__global__ void init_accum_kernel(float* accum) {
  if (threadIdx.x < 4) accum[threadIdx.x] = 0.f;
}

__global__ void sproj_kernel(const float* __restrict__ s, const float* __restrict__ Ws,
                             float* __restrict__ sproj) {
  int p = blockIdx.x, tid = threadIdx.x;
  const float* row = s + (size_t)p * 1024;
  float sum = 0.f;
#pragma unroll
  for (int k0 = 0; k0 < 1024; k0 += 256) sum += row[k0 + tid] * Ws[k0 + tid];
#pragma unroll
  for (int m = 1; m < 64; m <<= 1) sum += __shfl_xor(sum, m, 64);
  __shared__ float red[4];
  if ((tid & 63) == 0) red[tid >> 6] = sum;
  __syncthreads();
  if (tid == 0) sproj[p] = red[0] + red[1] + red[2] + red[3];
}

// wave handles 16 positions (position = lane&15 within the wave's group)
__global__ void difficulty_mfma(const float* __restrict__ s, const short* __restrict__ PWd1,
                                const float* __restrict__ bd1, const float* __restrict__ Wd2,
                                const float* __restrict__ bd2, float* __restrict__ probsv,
                                float* __restrict__ accum) {
  int tid = threadIdx.x;
  int wave = tid >> 6, lane = tid & 63, n = lane & 15, g = lane >> 4;
  int p0 = (blockIdx.x * 4 + wave) * 16;
  const float* sg = s + (size_t)(p0 + n) * 1024;
  f32x4 ha[8];
  const f32x4 Z = {0.f, 0.f, 0.f, 0.f};
#pragma unroll
  for (int t = 0; t < 8; t++) ha[t] = Z;
  for (int kc = 0; kc < 32; kc++) {
    f32x4 x0 = *(const f32x4*)(sg + 32 * kc + 4 * g);
    f32x4 x1 = *(const f32x4*)(sg + 32 * kc + 16 + 4 * g);
    short8 sb;
#pragma unroll
    for (int c = 0; c < 4; c++) { sb[c] = bf16rne(x0[c]); sb[c + 4] = bf16rne(x1[c]); }
#pragma unroll
    for (int t = 0; t < 8; t++) ha[t] = MF(ldfrag(PWd1, t, kc, 32, lane), sb, ha[t]);
  }
  float v0 = 0.f, v1 = 0.f, v2 = 0.f;
#pragma unroll
  for (int t = 0; t < 8; t++)
#pragma unroll
    for (int c = 0; c < 4; c++) {
      int hid = 16 * t + 4 * g + c;
      float u = fmaxf(ha[t][c] + bd1[hid], 0.f);
      v0 += u * Wd2[hid * 3 + 0];
      v1 += u * Wd2[hid * 3 + 1];
      v2 += u * Wd2[hid * 3 + 2];
    }
  v0 += __shfl_xor(v0, 16, 64); v0 += __shfl_xor(v0, 32, 64);
  v1 += __shfl_xor(v1, 16, 64); v1 += __shfl_xor(v1, 32, 64);
  v2 += __shfl_xor(v2, 16, 64); v2 += __shfl_xor(v2, 32, 64);
  if (g == 0) {
    float l0 = v0 + bd2[0], l1 = v1 + bd2[1], l2 = v2 + bd2[2];
    float mx = fmaxf(l0, fmaxf(l1, l2));
    float e0 = __expf(l0 - mx), e1 = __expf(l1 - mx), e2 = __expf(l2 - mx);
    float inv = 1.f / (e0 + e1 + e2);
    float p0v = e0 * inv, p1v = e1 * inv, p2v = e2 * inv;
    int p = p0 + n;
    probsv[p * 3 + 0] = p0v; probsv[p * 3 + 1] = p1v; probsv[p * 3 + 2] = p2v;
    atomicAdd(accum + 0, p0v);
    atomicAdd(accum + 1, p1v);
    atomicAdd(accum + 2, p2v);
    atomicAdd(accum + 3, p0v * 1.f + p1v * 2.f + p2v * 4.f);
  }
}

// wave per position: mask[n] = sigmoid(sum_hid relu(r@Wa1+ba1)*Wa2 + ba2 + sproj)
__global__ void slot_mask_mfma(const float* __restrict__ r, const short* __restrict__ PWa1,
                               const float* __restrict__ ba1, const float* __restrict__ Wa2,
                               const float* __restrict__ ba2, const float* __restrict__ sproj,
                               float* __restrict__ mask) {
  int tid = threadIdx.x;
  int wave = tid >> 6, lane = tid & 63, n = lane & 15, g = lane >> 4;
  int p = blockIdx.x * 4 + wave;
  const float* rsg = r + (size_t)p * 4096 + n * 256;
  short8 rb[8];
#pragma unroll
  for (int kc = 0; kc < 8; kc++) {
    f32x4 x0 = *(const f32x4*)(rsg + 32 * kc + 4 * g);
    f32x4 x1 = *(const f32x4*)(rsg + 32 * kc + 16 + 4 * g);
    short8 o;
#pragma unroll
    for (int c = 0; c < 4; c++) { o[c] = bf16rne(x0[c]); o[c + 4] = bf16rne(x1[c]); }
    rb[kc] = o;
  }
  f32x4 ha[8];
  const f32x4 Z = {0.f, 0.f, 0.f, 0.f};
#pragma unroll
  for (int t = 0; t < 8; t++) ha[t] = Z;
#pragma unroll
  for (int kc = 0; kc < 8; kc++)
#pragma unroll
    for (int t = 0; t < 8; t++) ha[t] = MF(ldfrag(PWa1, t, kc, 8, lane), rb[kc], ha[t]);
  float v = 0.f;
#pragma unroll
  for (int t = 0; t < 8; t++)
#pragma unroll
    for (int c = 0; c < 4; c++) {
      int hid = 16 * t + 4 * g + c;
      v += fmaxf(ha[t][c] + ba1[hid], 0.f) * Wa2[hid];
    }
  v += __shfl_xor(v, 16, 64);
  v += __shfl_xor(v, 32, 64);
  if (g == 0) mask[p * 16 + n] = 1.f / (1.f + __expf(-(v + ba2[0] + sproj[p])));
}

__global__ __launch_bounds__(256, 2) void reason_mfma(
    const float* __restrict__ r_src, float* __restrict__ r_dst,
    const float* __restrict__ maskg, const float* __restrict__ probsv,
    float* __restrict__ outp, int cand_idx,
    const short* __restrict__ PWq, const short* __restrict__ PWk,
    const short* __restrict__ PWv, const short* __restrict__ PWo,
    const short* __restrict__ PWf1, const short* __restrict__ PWf2,
    const float* __restrict__ ln1s, const float* __restrict__ ln1b,
    const float* __restrict__ ln2s, const float* __restrict__ ln2b,
    const float* __restrict__ bf1g, const float* __restrict__ bf2g) {
  __shared__ __align__(16) float P_ln1s[256], P_ln1b[256], P_ln2s[256], P_ln2b[256];
  __shared__ __align__(16) float P_bf1[1024], P_bf2[256];
  __shared__ __align__(16) float lds_r[16384];  // 4 waves x 16x256 f32, swizzled
  const int tid = threadIdx.x;
  P_ln1s[tid] = ln1s[tid]; P_ln1b[tid] = ln1b[tid];
  P_ln2s[tid] = ln2s[tid]; P_ln2b[tid] = ln2b[tid];
  P_bf2[tid] = bf2g[tid];
  for (int i = tid; i < 1024; i += 256) P_bf1[i] = bf1g[i];
  __syncthreads();

  const int wave = tid >> 6, lane = tid & 63;
  const int n = lane & 15, g = lane >> 4;
  const int p = blockIdx.x * 4 + wave;
  const size_t base = (size_t)p * 4096;
  const int rbase = wave * 4096;
  const f32x4 Z = {0.f, 0.f, 0.f, 0.f};

  // swizzled f32 element index inside this wave's r tile
  auto ridx = [&](int row, int k) { return rbase + ((row * 256 + k) ^ ((row & 7) << 2)); };

  const float maskn = maskg[p * 16 + n];

  // ---- load r (standard layout, 64B-coalesced) into swizzled LDS ----
  {
    const float* rsg = r_src + base + n * 256;
#pragma unroll
    for (int kc = 0; kc < 8; kc++) {
      f32x4 x0 = *(const f32x4*)(rsg + 32 * kc + 4 * g);
      f32x4 x1 = *(const f32x4*)(rsg + 32 * kc + 16 + 4 * g);
      *(f32x4*)&lds_r[ridx(n, 32 * kc + 4 * g)] = x0;
      *(f32x4*)&lds_r[ridx(n, 32 * kc + 16 + 4 * g)] = x1;
    }
  }

  short8 h1[8];
  auto do_ln = [&](const float* sc, const float* bi, short8* h) {
    f32x4 a[8], b[8];
    float sum = 0.f, sq = 0.f;
#pragma unroll
    for (int kc = 0; kc < 8; kc++) {
      a[kc] = *(const f32x4*)&lds_r[ridx(n, 32 * kc + 4 * g)];
      b[kc] = *(const f32x4*)&lds_r[ridx(n, 32 * kc + 16 + 4 * g)];
#pragma unroll
      for (int c = 0; c < 4; c++) {
        sum += a[kc][c] + b[kc][c];
        sq += a[kc][c] * a[kc][c] + b[kc][c] * b[kc][c];
      }
    }
    sum += __shfl_xor(sum, 16, 64); sq += __shfl_xor(sq, 16, 64);
    sum += __shfl_xor(sum, 32, 64); sq += __shfl_xor(sq, 32, 64);
    float mu = sum * (1.f / 256.f);
    float inv = rsqrtf(sq * (1.f / 256.f) - mu * mu + 1e-5f);
#pragma unroll
    for (int kc = 0; kc < 8; kc++) {
      f32x4 s0 = *(const f32x4*)&sc[32 * kc + 4 * g];
      f32x4 b0 = *(const f32x4*)&bi[32 * kc + 4 * g];
      f32x4 s1 = *(const f32x4*)&sc[32 * kc + 16 + 4 * g];
      f32x4 b1 = *(const f32x4*)&bi[32 * kc + 16 + 4 * g];
      short8 hh;
#pragma unroll
      for (int c = 0; c < 4; c++) {
        hh[c]     = bf16rne((a[kc][c] - mu) * inv * s0[c] + b0[c]);
        hh[c + 4] = bf16rne((b[kc][c] - mu) * inv * s1[c] + b1[c]);
      }
      h[kc] = hh;
    }
  };

  // ================= attention =================
  do_ln(P_ln1s, P_ln1b, h1);

  short8 ob[8];
#pragma unroll
  for (int hh = 0; hh < 4; hh++) {
    f32x4 qa[4], ka[4], va[4];
#pragma unroll
    for (int t = 0; t < 4; t++) { qa[t] = Z; ka[t] = Z; va[t] = Z; }
#pragma unroll
    for (int kc = 0; kc < 8; kc++) {
      short8 hb = h1[kc];
#pragma unroll
      for (int t = 0; t < 4; t++) qa[t] = MF(ldfrag(PWq, 4 * hh + t, kc, 8, lane), hb, qa[t]);
#pragma unroll
      for (int t = 0; t < 4; t++) ka[t] = MF(ldfrag(PWk, 4 * hh + t, kc, 8, lane), hb, ka[t]);
#pragma unroll
      for (int t = 0; t < 4; t++) va[t] = MF(hb, ldfrag(PWv, 4 * hh + t, kc, 8, lane), va[t]);
    }
    short8 qb[2], kb[2];
#pragma unroll
    for (int c = 0; c < 2; c++) {
      short8 x, y;
#pragma unroll
      for (int jj = 0; jj < 8; jj++) {
        x[jj] = bf16rne(qa[2 * c + (jj >> 2)][jj & 3]);
        y[jj] = bf16rne(ka[2 * c + (jj >> 2)][jj & 3]);
      }
      qb[c] = x; kb[c] = y;
    }
    // scoresT[m][n] per head, then softmax over m (rows + cross-lane g)
    f32x4 sc = Z;
    sc = MF(kb[0], qb[0], sc);
    sc = MF(kb[1], qb[1], sc);
#pragma unroll
    for (int c = 0; c < 4; c++) sc[c] *= 0.125f;
    float mx = fmaxf(fmaxf(sc[0], sc[1]), fmaxf(sc[2], sc[3]));
    mx = fmaxf(mx, __shfl_xor(mx, 16, 64));
    mx = fmaxf(mx, __shfl_xor(mx, 32, 64));
    float e0 = __expf(sc[0] - mx), e1 = __expf(sc[1] - mx);
    float e2 = __expf(sc[2] - mx), e3 = __expf(sc[3] - mx);
    float sm = e0 + e1 + e2 + e3;
    sm += __shfl_xor(sm, 16, 64);
    sm += __shfl_xor(sm, 32, 64);
    float isv = 1.f / sm;
    short8 pb;
    pb[0] = bf16rne(e0 * isv); pb[1] = bf16rne(e1 * isv);
    pb[2] = bf16rne(e2 * isv); pb[3] = bf16rne(e3 * isv);
    pb[4] = 0; pb[5] = 0; pb[6] = 0; pb[7] = 0;
    short8 vb[4];
#pragma unroll
    for (int t = 0; t < 4; t++) {
      short8 x;
      x[0] = bf16rne(va[t][0]); x[1] = bf16rne(va[t][1]);
      x[2] = bf16rne(va[t][2]); x[3] = bf16rne(va[t][3]);
      x[4] = 0; x[5] = 0; x[6] = 0; x[7] = 0;
      vb[t] = x;
    }
    f32x4 oh[4];
#pragma unroll
    for (int t = 0; t < 4; t++) { oh[t] = Z; oh[t] = MF(vb[t], pb, oh[t]); }
#pragma unroll
    for (int c = 0; c < 2; c++) {
      short8 x;
#pragma unroll
      for (int jj = 0; jj < 8; jj++) x[jj] = bf16rne(oh[2 * c + (jj >> 2)][jj & 3]);
      ob[2 * hh + c] = x;
    }
  }

  // ---- r += mask * (o @ Wo) ----
  {
    f32x4 c2[16];
#pragma unroll
    for (int t = 0; t < 16; t++) c2[t] = Z;
#pragma unroll
    for (int kc = 0; kc < 8; kc++) {
      short8 bo = ob[kc];
#pragma unroll
      for (int t = 0; t < 16; t++) c2[t] = MF(ldfrag(PWo, t, kc, 8, lane), bo, c2[t]);
    }
#pragma unroll
    for (int kc = 0; kc < 8; kc++) {
      float* a0 = &lds_r[ridx(n, 32 * kc + 4 * g)];
      float* a1 = &lds_r[ridx(n, 32 * kc + 16 + 4 * g)];
      f32x4 x0 = *(f32x4*)a0, x1 = *(f32x4*)a1;
#pragma unroll
      for (int c = 0; c < 4; c++) {
        x0[c] += maskn * c2[2 * kc][c];
        x1[c] += maskn * c2[2 * kc + 1][c];
      }
      *(f32x4*)a0 = x0; *(f32x4*)a1 = x1;
    }
  }

  // ================= FFN =================
  do_ln(P_ln2s, P_ln2b, h1);
  {
    f32x4 fo[16];
#pragma unroll
    for (int t = 0; t < 16; t++) fo[t] = Z;
    for (int hc = 0; hc < 32; hc++) {
      f32x4 ht0 = Z, ht1 = Z;
#pragma unroll
      for (int kc = 0; kc < 8; kc++) {
        short8 hb = h1[kc];
        ht0 = MF(ldfrag(PWf1, 2 * hc, kc, 8, lane), hb, ht0);
        ht1 = MF(ldfrag(PWf1, 2 * hc + 1, kc, 8, lane), hb, ht1);
      }
      f32x4 u0 = *(const f32x4*)&P_bf1[32 * hc + 4 * g];
      f32x4 u1 = *(const f32x4*)&P_bf1[32 * hc + 16 + 4 * g];
      short8 hbb;
#pragma unroll
      for (int c = 0; c < 4; c++) {
        hbb[c]     = bf16rne(fast_gelu(ht0[c] + u0[c]));
        hbb[c + 4] = bf16rne(fast_gelu(ht1[c] + u1[c]));
      }
#pragma unroll
      for (int t = 0; t < 16; t++) fo[t] = MF(ldfrag(PWf2, t, hc, 32, lane), hbb, fo[t]);
    }
#pragma unroll
    for (int kc = 0; kc < 8; kc++) {
      f32x4 b0 = *(const f32x4*)&P_bf2[32 * kc + 4 * g];
      f32x4 b1 = *(const f32x4*)&P_bf2[32 * kc + 16 + 4 * g];
      float* a0 = &lds_r[ridx(n, 32 * kc + 4 * g)];
      float* a1 = &lds_r[ridx(n, 32 * kc + 16 + 4 * g)];
      f32x4 x0 = *(f32x4*)a0, x1 = *(f32x4*)a1;
#pragma unroll
      for (int c = 0; c < 4; c++) {
        x0[c] += maskn * (fo[2 * kc][c] + b0[c]);
        x1[c] += maskn * (fo[2 * kc + 1][c] + b1[c]);
      }
      *(f32x4*)a0 = x0; *(f32x4*)a1 = x1;
    }
  }

  // ---- store r_next; candidate accumulate ----
  {
    float w = (cand_idx >= 0) ? probsv[p * 3 + cand_idx] : 0.f;
    float* rd = r_dst + base + n * 256;
    float* op = outp + base + n * 256;
#pragma unroll
    for (int kc = 0; kc < 8; kc++) {
      f32x4 x0 = *(f32x4*)&lds_r[ridx(n, 32 * kc + 4 * g)];
      f32x4 x1 = *(f32x4*)&lds_r[ridx(n, 32 * kc + 16 + 4 * g)];
      *(f32x4*)(rd + 32 * kc + 4 * g) = x0;
      *(f32x4*)(rd + 32 * kc + 16 + 4 * g) = x1;
      if (cand_idx == 0) {
        f32x4 o0, o1;
#pragma unroll
        for (int c = 0; c < 4; c++) { o0[c] = w * x0[c]; o1[c] = w * x1[c]; }
        *(f32x4*)(op + 32 * kc + 4 * g) = o0;
        *(f32x4*)(op + 32 * kc + 16 + 4 * g) = o1;
      } else if (cand_idx > 0) {
        f32x4 o0 = *(f32x4*)(op + 32 * kc + 4 * g);
        f32x4 o1 = *(f32x4*)(op + 32 * kc + 16 + 4 * g);
#pragma unroll
        for (int c = 0; c < 4; c++) { o0[c] += w * x0[c]; o1[c] += w * x1[c]; }
        *(f32x4*)(op + 32 * kc + 4 * g) = o0;
        *(f32x4*)(op + 32 * kc + 16 + 4 * g) = o1;
      }
    }
  }
}

__global__ void finalize_kernel(const float* __restrict__ accum, float* __restrict__ dst) {
  const float inv = 1.f / 4096.f;
  float m0 = accum[0] * inv, m1 = accum[1] * inv, m2 = accum[2] * inv;
  const float u = 1.f / 3.f;
  float d0 = m0 - u, d1 = m1 - u, d2 = m2 - u;
  dst[0] = (d0 * d0 + d1 * d1 + d2 * d2) * (1.f / 3.f);
  dst[1] = accum[3] * inv;
}

extern "C" void kernel_launch(void* const* d_in, const int* in_sizes, int n_in,
                              void* d_out, int out_size, void* d_ws, size_t ws_size,
                              hipStream_t stream) {
  const float* s    = (const float*)d_in[0];
  const float* r    = (const float*)d_in[1];
  const float* Wd1  = (const float*)d_in[2];
  const float* bd1  = (const float*)d_in[3];
  const float* Wd2  = (const float*)d_in[4];
  const float* bd2  = (const float*)d_in[5];
  const float* Wa1  = (const float*)d_in[6];
  const float* ba1  = (const float*)d_in[7];
  const float* Wa2  = (const float*)d_in[8];
  const float* ba2  = (const float*)d_in[9];
  const float* Wsp  = (const float*)d_in[10];
  const float* ln1s = (const float*)d_in[11];
  const float* ln1b = (const float*)d_in[12];
  const float* Wq   = (const float*)d_in[13];
  const float* Wk   = (const float*)d_in[14];
  const float* Wv   = (const float*)d_in[15];
  const float* Wo   = (const float*)d_in[16];
  const float* ln2s = (const float*)d_in[17];
  const float* ln2b = (const float*)d_in[18];
  const float* Wf1  = (const float*)d_in[19];
  const float* bf1  = (const float*)d_in[20];
  const float* Wf2  = (const float*)d_in[21];
  const float* bf2  = (const float*)d_in[22];

  float* out = (float*)d_out;
  float* wsf = (float*)d_ws;
  float* mask   = wsf;
  float* sproj  = wsf + 65536;
  float* probsv = wsf + 65536 + 4096;
  float* accum  = wsf + 65536 + 4096 + 12288;
  float* r_cur  = wsf + 131072;
  short* pk     = (short*)(wsf + 131072 + 16777216);
  short* PWq  = pk;            // 65536
  short* PWk  = pk + 65536;    // 65536
  short* PWv  = pk + 131072;   // 65536
  short* PWo  = pk + 196608;   // 65536
  short* PWf1 = pk + 262144;   // 262144
  short* PWf2 = pk + 524288;   // 262144
  short* PWa1 = pk + 786432;   // 32768
  short* PWd1 = pk + 819200;   // 131072

  // ---- pack weights to bf16 fragment order ----
  pack_weight<<<32, 256, 0, stream>>>(Wq, PWq, 256, 256);
  pack_weight<<<32, 256, 0, stream>>>(Wk, PWk, 256, 256);
  pack_weight<<<32, 256, 0, stream>>>(Wv, PWv, 256, 256);
  pack_weight<<<32, 256, 0, stream>>>(Wo, PWo, 256, 256);
  pack_weight<<<128, 256, 0, stream>>>(Wf1, PWf1, 256, 1024);
  pack_weight<<<128, 256, 0, stream>>>(Wf2, PWf2, 1024, 256);
  pack_weight<<<16, 256, 0, stream>>>(Wa1, PWa1, 256, 128);
  pack_weight<<<64, 256, 0, stream>>>(Wd1, PWd1, 1024, 128);

  init_accum_kernel<<<1, 64, 0, stream>>>(accum);
  sproj_kernel<<<NPOS, 256, 0, stream>>>(s, Wsp, sproj);
  difficulty_mfma<<<64, 256, 0, stream>>>(s, PWd1, bd1, Wd2, bd2, probsv, accum);
  slot_mask_mfma<<<NPOS / 4, 256, 0, stream>>>(r, PWa1, ba1, Wa2, ba2, sproj, mask);

  reason_mfma<<<NPOS / 4, 256, 0, stream>>>(r, r_cur, mask, probsv, out, 0,
      PWq, PWk, PWv, PWo, PWf1, PWf2, ln1s, ln1b, ln2s, ln2b, bf1, bf2);
  reason_mfma<<<NPOS / 4, 256, 0, stream>>>(r_cur, r_cur, mask, probsv, out, 1,
      PWq, PWk, PWv, PWo, PWf1, PWf2, ln1s, ln1b, ln2s, ln2b, bf1, bf2);
  reason_mfma<<<NPOS / 4, 256, 0, stream>>>(r_cur, r_cur, mask, probsv, out, -1,
      PWq, PWk, PWv, PWo, PWf1, PWf2, ln1s, ln1b, ln2s, ln2b, bf1, bf2);
  reason_mfma<<<NPOS / 4, 256, 0, stream>>>(r_cur, r_cur, mask, probsv, out, 2,
      PWq, PWk, PWv, PWo, PWf1, PWf2, ln1s, ln1b, ln2s, ln2b, bf1, bf2);

  finalize_kernel<<<1, 1, 0, stream>>>(accum, out + R_ELEMS);
}

// Round 3
// 825.976 us; speedup vs baseline: 11.5460x; 2.5366x over previous
//
#include <hip/hip_runtime.h>
#include <math.h>

// ============================================================================
// AuroraBlock round 3: MFMA + LDS-staged weight stream (consumption order).
//   - 4 positions/block (1/wave); r held in VGPRs (no lds_r).
//   - all step weights packed into ONE stream of 96 x 16KB chunks in exact
//     consumption order; 4-buffer LDS ring staged via global_load_lds(16B),
//     counted vmcnt(8) + raw s_barrier boundaries (loads fly across barriers).
// ws (floats): [0..65535] mask | [65536..69631] sproj | [69632..81919] probs
//   [81920..81923] accum | [131072 ..] r_cur (16777216)
//   shorts at float offset 16908288: Wstream(786432) PWa1(32768) PWd1(131072)
// d_out: [0..16777215] r_out, [16777216] routing_loss, [16777217] mean_k
// ============================================================================

#define NPOS 4096
#define R_ELEMS 16777216ull
#define NCHUNK 96

typedef __attribute__((ext_vector_type(8))) short short8;
typedef __attribute__((ext_vector_type(4))) float f32x4;

#define MF(a, b, c) __builtin_amdgcn_mfma_f32_16x16x32_bf16(a, b, c, 0, 0, 0)

__device__ __forceinline__ short bf16rne(float f) {
  union { float f; unsigned u; } v; v.f = f;
  unsigned r = v.u + 0x7FFFu + ((v.u >> 16) & 1u);
  return (short)(r >> 16);
}

__device__ __forceinline__ float fast_gelu(float x) {
  float x3 = x * x * x;
  float z = 0.7978845608028654f * (x + 0.044715f * x3);
  float e = __expf(2.f * z);
  float t = 1.f - 2.f / (e + 1.f);
  return 0.5f * x * (1.f + t);
}

// ---- packing for difficulty/slot_mask (fragment-array layout, as round 2) ----
__global__ void pack_weight(const float* __restrict__ W, short* __restrict__ P,
                            int K, int N) {
  int id = blockIdx.x * 256 + threadIdx.x;
  int KC = K >> 5, T = N >> 4;
  if (id >= T * KC * 64) return;
  int l = id & 63, kc = (id >> 6) % KC, t = id / (64 * KC);
  int g = l >> 4, n = l & 15;
  short8 o;
#pragma unroll
  for (int jj = 0; jj < 8; jj++) {
    int k = 32 * kc + 4 * g + (jj & 3) + 16 * (jj >> 2);
    o[jj] = bf16rne(W[(size_t)k * N + 16 * t + n]);
  }
  *(short8*)(P + (size_t)id * 8) = o;
}

// ---- pack reasoning weights into consumption-order stream ----
// frag f (0..1535): per hh(4): Wq tiles 4hh..4hh+3 (kc-inner), Wk, Wv  [384]
//                   Wo t 0..15 kc 0..7                                 [128]
//                   per hc(32): Wf1 t=2hc,2hc+1 kc 0..7; Wf2 t 0..15 kc=hc [1024]
__global__ void pack_stream(const float* __restrict__ Wq, const float* __restrict__ Wk,
                            const float* __restrict__ Wv, const float* __restrict__ Wo,
                            const float* __restrict__ Wf1, const float* __restrict__ Wf2,
                            short* __restrict__ S) {
  int id = blockIdx.x * 256 + threadIdx.x;
  int f = id >> 6, lane = id & 63;
  if (f >= 1536) return;
  const float* W; int ldN, t, kc;
  if (f < 384) {
    int hh = f / 96, rem = f % 96, mat = rem / 32, r2 = rem % 32;
    t = 4 * hh + r2 / 8; kc = r2 % 8; ldN = 256;
    W = (mat == 0) ? Wq : (mat == 1) ? Wk : Wv;
  } else if (f < 512) {
    int gg = f - 384; t = gg / 8; kc = gg % 8; ldN = 256; W = Wo;
  } else {
    int gg = f - 512, hc = gg / 32, r2 = gg % 32;
    if (r2 < 16) { W = Wf1; ldN = 1024; t = 2 * hc + r2 / 8; kc = r2 % 8; }
    else         { W = Wf2; ldN = 256;  t = r2 - 16;         kc = hc;    }
  }
  int g = lane >> 4, n = lane & 15;
  short8 o;
#pragma unroll
  for (int jj = 0; jj < 8; jj++) {
    int k = 32 * kc + 4 * g + (jj & 3) + 16 * (jj >> 2);
    o[jj] = bf16rne(W[(size_t)k * ldN + 16 * t + n]);
  }
  *(short8*)(S + (size_t)f * 512 + lane * 8) = o;
}

__device__ __forceinline__ short8 ldfrag(const short* __restrict__ P, int t, int kc,
                                         int KC, int lane) {
  return *(const short8*)(P + ((size_t)((t * KC + kc) * 64 + lane) << 3));
}

__global__ void init_accum_kernel(float* accum) {
  if (threadIdx.x < 4) accum[threadIdx.x] = 0.f;
}

__global__ void sproj_kernel(const float* __restrict__ s, const float* __restrict__ Ws,
                             float* __restrict__ sproj) {
  int p = blockIdx.x, tid = threadIdx.x;
  const float* row = s + (size_t)p * 1024;
  float sum = 0.f;
#pragma unroll
  for (int k0 = 0; k0 < 1024; k0 += 256) sum += row[k0 + tid] * Ws[k0 + tid];
#pragma unroll
  for (int m = 1; m < 64; m <<= 1) sum += __shfl_xor(sum, m, 64);
  __shared__ float red[4];
  if ((tid & 63) == 0) red[tid >> 6] = sum;
  __syncthreads();
  if (tid == 0) sproj[p] = red[0] + red[1] + red[2] + red[3];
}

__global__ void difficulty_mfma(const float* __restrict__ s, const short* __restrict__ PWd1,
                                const float* __restrict__ bd1, const float* __restrict__ Wd2,
                                const float* __restrict__ bd2, float* __restrict__ probsv,
                                float* __restrict__ accum) {
  int tid = threadIdx.x;
  int wave = tid >> 6, lane = tid & 63, n = lane & 15, g = lane >> 4;
  int p0 = (blockIdx.x * 4 + wave) * 16;
  const float* sg = s + (size_t)(p0 + n) * 1024;
  f32x4 ha[8];
  const f32x4 Z = {0.f, 0.f, 0.f, 0.f};
#pragma unroll
  for (int t = 0; t < 8; t++) ha[t] = Z;
  for (int kc = 0; kc < 32; kc++) {
    f32x4 x0 = *(const f32x4*)(sg + 32 * kc + 4 * g);
    f32x4 x1 = *(const f32x4*)(sg + 32 * kc + 16 + 4 * g);
    short8 sb;
#pragma unroll
    for (int c = 0; c < 4; c++) { sb[c] = bf16rne(x0[c]); sb[c + 4] = bf16rne(x1[c]); }
#pragma unroll
    for (int t = 0; t < 8; t++) ha[t] = MF(ldfrag(PWd1, t, kc, 32, lane), sb, ha[t]);
  }
  float v0 = 0.f, v1 = 0.f, v2 = 0.f;
#pragma unroll
  for (int t = 0; t < 8; t++)
#pragma unroll
    for (int c = 0; c < 4; c++) {
      int hid = 16 * t + 4 * g + c;
      float u = fmaxf(ha[t][c] + bd1[hid], 0.f);
      v0 += u * Wd2[hid * 3 + 0];
      v1 += u * Wd2[hid * 3 + 1];
      v2 += u * Wd2[hid * 3 + 2];
    }
  v0 += __shfl_xor(v0, 16, 64); v0 += __shfl_xor(v0, 32, 64);
  v1 += __shfl_xor(v1, 16, 64); v1 += __shfl_xor(v1, 32, 64);
  v2 += __shfl_xor(v2, 16, 64); v2 += __shfl_xor(v2, 32, 64);
  if (g == 0) {
    float l0 = v0 + bd2[0], l1 = v1 + bd2[1], l2 = v2 + bd2[2];
    float mx = fmaxf(l0, fmaxf(l1, l2));
    float e0 = __expf(l0 - mx), e1 = __expf(l1 - mx), e2 = __expf(l2 - mx);
    float inv = 1.f / (e0 + e1 + e2);
    float p0v = e0 * inv, p1v = e1 * inv, p2v = e2 * inv;
    int p = p0 + n;
    probsv[p * 3 + 0] = p0v; probsv[p * 3 + 1] = p1v; probsv[p * 3 + 2] = p2v;
    atomicAdd(accum + 0, p0v);
    atomicAdd(accum + 1, p1v);
    atomicAdd(accum + 2, p2v);
    atomicAdd(accum + 3, p0v * 1.f + p1v * 2.f + p2v * 4.f);
  }
}

__global__ void slot_mask_mfma(const float* __restrict__ r, const short* __restrict__ PWa1,
                               const float* __restrict__ ba1, const float* __restrict__ Wa2,
                               const float* __restrict__ ba2, const float* __restrict__ sproj,
                               float* __restrict__ mask) {
  int tid = threadIdx.x;
  int wave = tid >> 6, lane = tid & 63, n = lane & 15, g = lane >> 4;
  int p = blockIdx.x * 4 + wave;
  const float* rsg = r + (size_t)p * 4096 + n * 256;
  short8 rb[8];
#pragma unroll
  for (int kc = 0; kc < 8; kc++) {
    f32x4 x0 = *(const f32x4*)(rsg + 32 * kc + 4 * g);
    f32x4 x1 = *(const f32x4*)(rsg + 32 * kc + 16 + 4 * g);
    short8 o;
#pragma unroll
    for (int c = 0; c < 4; c++) { o[c] = bf16rne(x0[c]); o[c + 4] = bf16rne(x1[c]); }
    rb[kc] = o;
  }
  f32x4 ha[8];
  const f32x4 Z = {0.f, 0.f, 0.f, 0.f};
#pragma unroll
  for (int t = 0; t < 8; t++) ha[t] = Z;
#pragma unroll
  for (int kc = 0; kc < 8; kc++)
#pragma unroll
    for (int t = 0; t < 8; t++) ha[t] = MF(ldfrag(PWa1, t, kc, 8, lane), rb[kc], ha[t]);
  float v = 0.f;
#pragma unroll
  for (int t = 0; t < 8; t++)
#pragma unroll
    for (int c = 0; c < 4; c++) {
      int hid = 16 * t + 4 * g + c;
      v += fmaxf(ha[t][c] + ba1[hid], 0.f) * Wa2[hid];
    }
  v += __shfl_xor(v, 16, 64);
  v += __shfl_xor(v, 32, 64);
  if (g == 0) mask[p * 16 + n] = 1.f / (1.f + __expf(-(v + ba2[0] + sproj[p])));
}

// ============================ reasoning step ================================
__global__ __launch_bounds__(256, 2) void reason_mfma(
    const float* __restrict__ r_src, float* __restrict__ r_dst,
    const float* __restrict__ maskg, const float* __restrict__ probsv,
    float* __restrict__ outp, int cand_idx, const short* __restrict__ Wstream,
    const float* __restrict__ ln1s, const float* __restrict__ ln1b,
    const float* __restrict__ ln2s, const float* __restrict__ ln2b,
    const float* __restrict__ bf1g, const float* __restrict__ bf2g) {
  __shared__ __align__(16) short Wbuf[4 * 8192];  // 4 x 16KB ring
  __shared__ __align__(16) float P_ln1s[256], P_ln1b[256], P_ln2s[256], P_ln2b[256];
  __shared__ __align__(16) float P_bf1[1024], P_bf2[256];
  const int tid = threadIdx.x;
  P_ln1s[tid] = ln1s[tid]; P_ln1b[tid] = ln1b[tid];
  P_ln2s[tid] = ln2s[tid]; P_ln2b[tid] = ln2b[tid];
  P_bf2[tid] = bf2g[tid];
  for (int i = tid; i < 1024; i += 256) P_bf1[i] = bf1g[i];
  __syncthreads();

  const int wave = tid >> 6, lane = tid & 63;
  const int n = lane & 15, g = lane >> 4;
  const int p = blockIdx.x * 4 + wave;
  const size_t base = (size_t)p * 4096;
  const f32x4 Z = {0.f, 0.f, 0.f, 0.f};

  // ---- prologue: r -> regs, mask/prob (compiler inserts waits on use) ----
  f32x4 r0[8], r1[8];
  {
    const float* rsg = r_src + base + n * 256;
#pragma unroll
    for (int kc = 0; kc < 8; kc++) {
      r0[kc] = *(const f32x4*)(rsg + 32 * kc + 4 * g);
      r1[kc] = *(const f32x4*)(rsg + 32 * kc + 16 + 4 * g);
    }
  }
  const float maskn = maskg[p * 16 + n];
  const float w = (cand_idx >= 0) ? probsv[p * 3 + cand_idx] : 0.f;

  // ---- staging machinery ----
  auto stage_issue = [&](int c) {
    const short* gs = Wstream + (size_t)c * 8192 + wave * 512 + lane * 8;
    short* ld = (short*)Wbuf + (c & 3) * 8192 + wave * 512;  // wave-uniform dest
#pragma unroll
    for (int i = 0; i < 4; ++i)
      __builtin_amdgcn_global_load_lds(
          (const __attribute__((address_space(1))) void*)(gs + i * 2048),
          (__attribute__((address_space(3))) void*)(ld + i * 2048), 16, 0, 0);
  };
  stage_issue(0); stage_issue(1); stage_issue(2);

  int cidx = 0;
  auto boundary = [&]() -> const short* {
    int c = cidx++;
    if (c < 94) {
      asm volatile("s_waitcnt vmcnt(8) lgkmcnt(0)\ns_barrier" ::: "memory");
    } else {
      asm volatile("s_waitcnt vmcnt(0) lgkmcnt(0)\ns_barrier" ::: "memory");
    }
    __builtin_amdgcn_sched_barrier(0);
    if (c + 3 < NCHUNK) stage_issue(c + 3);
    return &Wbuf[(c & 3) * 8192];
  };
#define FRAG(Bp, i) (*(const short8*)((Bp) + (i) * 512 + lane * 8))

  short8 h1[8];
  auto do_ln = [&](const float* sc, const float* bi, short8* h) {
    float sum = 0.f, sq = 0.f;
#pragma unroll
    for (int kc = 0; kc < 8; kc++)
#pragma unroll
      for (int c = 0; c < 4; c++) {
        sum += r0[kc][c] + r1[kc][c];
        sq += r0[kc][c] * r0[kc][c] + r1[kc][c] * r1[kc][c];
      }
    sum += __shfl_xor(sum, 16, 64); sq += __shfl_xor(sq, 16, 64);
    sum += __shfl_xor(sum, 32, 64); sq += __shfl_xor(sq, 32, 64);
    float mu = sum * (1.f / 256.f);
    float inv = rsqrtf(sq * (1.f / 256.f) - mu * mu + 1e-5f);
#pragma unroll
    for (int kc = 0; kc < 8; kc++) {
      f32x4 s0 = *(const f32x4*)&sc[32 * kc + 4 * g];
      f32x4 b0 = *(const f32x4*)&bi[32 * kc + 4 * g];
      f32x4 s1 = *(const f32x4*)&sc[32 * kc + 16 + 4 * g];
      f32x4 b1 = *(const f32x4*)&bi[32 * kc + 16 + 4 * g];
      short8 hh;
#pragma unroll
      for (int c = 0; c < 4; c++) {
        hh[c]     = bf16rne((r0[kc][c] - mu) * inv * s0[c] + b0[c]);
        hh[c + 4] = bf16rne((r1[kc][c] - mu) * inv * s1[c] + b1[c]);
      }
      h[kc] = hh;
    }
  };

  // ================= attention =================
  do_ln(P_ln1s, P_ln1b, h1);

  short8 ob[8];
#pragma unroll
  for (int hh = 0; hh < 4; hh++) {
    f32x4 qa[4], ka[4], va[4];
#pragma unroll
    for (int t = 0; t < 4; t++) { qa[t] = Z; ka[t] = Z; va[t] = Z; }
#pragma unroll
    for (int tp = 0; tp < 2; tp++) {
      const short* B = boundary();
#pragma unroll
      for (int tt = 0; tt < 2; tt++)
#pragma unroll
        for (int kc = 0; kc < 8; kc++)
          qa[2 * tp + tt] = MF(FRAG(B, tt * 8 + kc), h1[kc], qa[2 * tp + tt]);
    }
#pragma unroll
    for (int tp = 0; tp < 2; tp++) {
      const short* B = boundary();
#pragma unroll
      for (int tt = 0; tt < 2; tt++)
#pragma unroll
        for (int kc = 0; kc < 8; kc++)
          ka[2 * tp + tt] = MF(FRAG(B, tt * 8 + kc), h1[kc], ka[2 * tp + tt]);
    }
#pragma unroll
    for (int tp = 0; tp < 2; tp++) {
      const short* B = boundary();
#pragma unroll
      for (int tt = 0; tt < 2; tt++)
#pragma unroll
        for (int kc = 0; kc < 8; kc++)
          va[2 * tp + tt] = MF(h1[kc], FRAG(B, tt * 8 + kc), va[2 * tp + tt]);
    }
    // scores^T, softmax over rows (reduce across g), PV — identical to round 2
    short8 qb[2], kb[2];
#pragma unroll
    for (int c = 0; c < 2; c++) {
      short8 x, y;
#pragma unroll
      for (int jj = 0; jj < 8; jj++) {
        x[jj] = bf16rne(qa[2 * c + (jj >> 2)][jj & 3]);
        y[jj] = bf16rne(ka[2 * c + (jj >> 2)][jj & 3]);
      }
      qb[c] = x; kb[c] = y;
    }
    f32x4 sc = Z;
    sc = MF(kb[0], qb[0], sc);
    sc = MF(kb[1], qb[1], sc);
#pragma unroll
    for (int c = 0; c < 4; c++) sc[c] *= 0.125f;
    float mx = fmaxf(fmaxf(sc[0], sc[1]), fmaxf(sc[2], sc[3]));
    mx = fmaxf(mx, __shfl_xor(mx, 16, 64));
    mx = fmaxf(mx, __shfl_xor(mx, 32, 64));
    float e0 = __expf(sc[0] - mx), e1 = __expf(sc[1] - mx);
    float e2 = __expf(sc[2] - mx), e3 = __expf(sc[3] - mx);
    float sm = e0 + e1 + e2 + e3;
    sm += __shfl_xor(sm, 16, 64);
    sm += __shfl_xor(sm, 32, 64);
    float isv = 1.f / sm;
    short8 pb;
    pb[0] = bf16rne(e0 * isv); pb[1] = bf16rne(e1 * isv);
    pb[2] = bf16rne(e2 * isv); pb[3] = bf16rne(e3 * isv);
    pb[4] = 0; pb[5] = 0; pb[6] = 0; pb[7] = 0;
    short8 vb[4];
#pragma unroll
    for (int t = 0; t < 4; t++) {
      short8 x;
      x[0] = bf16rne(va[t][0]); x[1] = bf16rne(va[t][1]);
      x[2] = bf16rne(va[t][2]); x[3] = bf16rne(va[t][3]);
      x[4] = 0; x[5] = 0; x[6] = 0; x[7] = 0;
      vb[t] = x;
    }
    f32x4 oh[4];
#pragma unroll
    for (int t = 0; t < 4; t++) { oh[t] = Z; oh[t] = MF(vb[t], pb, oh[t]); }
#pragma unroll
    for (int c = 0; c < 2; c++) {
      short8 x;
#pragma unroll
      for (int jj = 0; jj < 8; jj++) x[jj] = bf16rne(oh[2 * c + (jj >> 2)][jj & 3]);
      ob[2 * hh + c] = x;
    }
  }

  // ---- r += mask * (o @ Wo) ----
  {
    f32x4 c2[16];
#pragma unroll
    for (int t = 0; t < 16; t++) c2[t] = Z;
#pragma unroll
    for (int j = 0; j < 8; j++) {
      const short* B = boundary();
#pragma unroll
      for (int tt = 0; tt < 2; tt++)
#pragma unroll
        for (int kc = 0; kc < 8; kc++)
          c2[2 * j + tt] = MF(FRAG(B, tt * 8 + kc), ob[kc], c2[2 * j + tt]);
    }
#pragma unroll
    for (int kc = 0; kc < 8; kc++)
#pragma unroll
      for (int c = 0; c < 4; c++) {
        r0[kc][c] += maskn * c2[2 * kc][c];
        r1[kc][c] += maskn * c2[2 * kc + 1][c];
      }
  }

  // ================= FFN =================
  do_ln(P_ln2s, P_ln2b, h1);
  {
    f32x4 fo[16];
#pragma unroll
    for (int t = 0; t < 16; t++) fo[t] = Z;
    for (int hc = 0; hc < 32; hc++) {
      const short* B = boundary();
      f32x4 ht0 = Z, ht1 = Z;
#pragma unroll
      for (int kc = 0; kc < 8; kc++) ht0 = MF(FRAG(B, kc), h1[kc], ht0);
#pragma unroll
      for (int kc = 0; kc < 8; kc++) ht1 = MF(FRAG(B, 8 + kc), h1[kc], ht1);
      f32x4 u0 = *(const f32x4*)&P_bf1[32 * hc + 4 * g];
      f32x4 u1 = *(const f32x4*)&P_bf1[32 * hc + 16 + 4 * g];
      short8 hbb;
#pragma unroll
      for (int c = 0; c < 4; c++) {
        hbb[c]     = bf16rne(fast_gelu(ht0[c] + u0[c]));
        hbb[c + 4] = bf16rne(fast_gelu(ht1[c] + u1[c]));
      }
      B = boundary();
#pragma unroll
      for (int t = 0; t < 16; t++) fo[t] = MF(FRAG(B, t), hbb, fo[t]);
    }
#pragma unroll
    for (int kc = 0; kc < 8; kc++) {
      f32x4 b0 = *(const f32x4*)&P_bf2[32 * kc + 4 * g];
      f32x4 b1 = *(const f32x4*)&P_bf2[32 * kc + 16 + 4 * g];
#pragma unroll
      for (int c = 0; c < 4; c++) {
        r0[kc][c] += maskn * (fo[2 * kc][c] + b0[c]);
        r1[kc][c] += maskn * (fo[2 * kc + 1][c] + b1[c]);
      }
    }
  }

  // ---- store r_next; candidate accumulate ----
  {
    float* rd = r_dst + base + n * 256;
    float* op = outp + base + n * 256;
#pragma unroll
    for (int kc = 0; kc < 8; kc++) {
      *(f32x4*)(rd + 32 * kc + 4 * g) = r0[kc];
      *(f32x4*)(rd + 32 * kc + 16 + 4 * g) = r1[kc];
      if (cand_idx == 0) {
        f32x4 o0, o1;
#pragma unroll
        for (int c = 0; c < 4; c++) { o0[c] = w * r0[kc][c]; o1[c] = w * r1[kc][c]; }
        *(f32x4*)(op + 32 * kc + 4 * g) = o0;
        *(f32x4*)(op + 32 * kc + 16 + 4 * g) = o1;
      } else if (cand_idx > 0) {
        f32x4 o0 = *(f32x4*)(op + 32 * kc + 4 * g);
        f32x4 o1 = *(f32x4*)(op + 32 * kc + 16 + 4 * g);
#pragma unroll
        for (int c = 0; c < 4; c++) { o0[c] += w * r0[kc][c]; o1[c] += w * r1[kc][c]; }
        *(f32x4*)(op + 32 * kc + 4 * g) = o0;
        *(f32x4*)(op + 32 * kc + 16 + 4 * g) = o1;
      }
    }
  }
}

__global__ void finalize_kernel(const float* __restrict__ accum, float* __restrict__ dst) {
  const float inv = 1.f / 4096.f;
  float m0 = accum[0] * inv, m1 = accum[1] * inv, m2 = accum[2] * inv;
  const float u = 1.f / 3.f;
  float d0 = m0 - u, d1 = m1 - u, d2 = m2 - u;
  dst[0] = (d0 * d0 + d1 * d1 + d2 * d2) * (1.f / 3.f);
  dst[1] = accum[3] * inv;
}

extern "C" void kernel_launch(void* const* d_in, const int* in_sizes, int n_in,
                              void* d_out, int out_size, void* d_ws, size_t ws_size,
                              hipStream_t stream) {
  const float* s    = (const float*)d_in[0];
  const float* r    = (const float*)d_in[1];
  const float* Wd1  = (const float*)d_in[2];
  const float* bd1  = (const float*)d_in[3];
  const float* Wd2  = (const float*)d_in[4];
  const float* bd2  = (const float*)d_in[5];
  const float* Wa1  = (const float*)d_in[6];
  const float* ba1  = (const float*)d_in[7];
  const float* Wa2  = (const float*)d_in[8];
  const float* ba2  = (const float*)d_in[9];
  const float* Wsp  = (const float*)d_in[10];
  const float* ln1s = (const float*)d_in[11];
  const float* ln1b = (const float*)d_in[12];
  const float* Wq   = (const float*)d_in[13];
  const float* Wk   = (const float*)d_in[14];
  const float* Wv   = (const float*)d_in[15];
  const float* Wo   = (const float*)d_in[16];
  const float* ln2s = (const float*)d_in[17];
  const float* ln2b = (const float*)d_in[18];
  const float* Wf1  = (const float*)d_in[19];
  const float* bf1  = (const float*)d_in[20];
  const float* Wf2  = (const float*)d_in[21];
  const float* bf2  = (const float*)d_in[22];

  float* out = (float*)d_out;
  float* wsf = (float*)d_ws;
  float* mask   = wsf;
  float* sproj  = wsf + 65536;
  float* probsv = wsf + 65536 + 4096;
  float* accum  = wsf + 65536 + 4096 + 12288;
  float* r_cur  = wsf + 131072;
  short* pk     = (short*)(wsf + 131072 + 16777216);
  short* Wstream = pk;             // 786432 shorts (96 x 16KB)
  short* PWa1    = pk + 786432;    // 32768
  short* PWd1    = pk + 819200;    // 131072

  pack_stream<<<384, 256, 0, stream>>>(Wq, Wk, Wv, Wo, Wf1, Wf2, Wstream);
  pack_weight<<<16, 256, 0, stream>>>(Wa1, PWa1, 256, 128);
  pack_weight<<<64, 256, 0, stream>>>(Wd1, PWd1, 1024, 128);

  init_accum_kernel<<<1, 64, 0, stream>>>(accum);
  sproj_kernel<<<NPOS, 256, 0, stream>>>(s, Wsp, sproj);
  difficulty_mfma<<<64, 256, 0, stream>>>(s, PWd1, bd1, Wd2, bd2, probsv, accum);
  slot_mask_mfma<<<NPOS / 4, 256, 0, stream>>>(r, PWa1, ba1, Wa2, ba2, sproj, mask);

  reason_mfma<<<NPOS / 4, 256, 0, stream>>>(r, r_cur, mask, probsv, out, 0,
      Wstream, ln1s, ln1b, ln2s, ln2b, bf1, bf2);
  reason_mfma<<<NPOS / 4, 256, 0, stream>>>(r_cur, r_cur, mask, probsv, out, 1,
      Wstream, ln1s, ln1b, ln2s, ln2b, bf1, bf2);
  reason_mfma<<<NPOS / 4, 256, 0, stream>>>(r_cur, r_cur, mask, probsv, out, -1,
      Wstream, ln1s, ln1b, ln2s, ln2b, bf1, bf2);
  reason_mfma<<<NPOS / 4, 256, 0, stream>>>(r_cur, r_cur, mask, probsv, out, 2,
      Wstream, ln1s, ln1b, ln2s, ln2b, bf1, bf2);

  finalize_kernel<<<1, 1, 0, stream>>>(accum, out + R_ELEMS);
}